// Round 6
// baseline (416.883 us; speedup 1.0000x reference)
//
#include <hip/hip_runtime.h>
#include <hip/hip_bf16.h>

// Problem constants
#define NDIM 256   // outer n
#define QDIM 256   // q/k sequence
#define CDIM 128   // channels
#define HH 4       // heads
#define DD 32      // head dim
#define RROWS (NDIM * QDIM)  // 65536 flattened rows

// ---------- bf16 helpers ----------
__device__ __forceinline__ float bf2f(unsigned short u) {
    unsigned int x = ((unsigned int)u) << 16;
    return __uint_as_float(x);
}
__device__ __forceinline__ unsigned short f2bf(float f) {
    union { __bf16 b; unsigned short u; } cv;
    cv.b = (__bf16)f;   // HW RNE convert
    return cv.u;
}

// MFMA fragment types (gfx950: mfma_f32_16x16x32_bf16)
typedef __bf16 bf16x8v __attribute__((ext_vector_type(8)));
typedef float  f32x4v  __attribute__((ext_vector_type(4)));
union frag_u { uint4 u; bf16x8v v; };

__device__ __forceinline__ bf16x8v cvt8(float4 f0, float4 f1) {
    bf16x8v r;
    r[0] = (__bf16)f0.x; r[1] = (__bf16)f0.y; r[2] = (__bf16)f0.z; r[3] = (__bf16)f0.w;
    r[4] = (__bf16)f1.x; r[5] = (__bf16)f1.y; r[6] = (__bf16)f1.z; r[7] = (__bf16)f1.w;
    return r;
}

// =====================================================================
// Kernel 0a: weight prep. One block per matrix (5 blocks).
// wt[p][n][k] = bf16(W_p[k][n])   (transposed so B-frags are contiguous)
// =====================================================================
__global__ __launch_bounds__(256, 1) void prep_weights(
    const float* __restrict__ Wq, const float* __restrict__ Wk,
    const float* __restrict__ Wv, const float* __restrict__ Wg,
    const float* __restrict__ Wo, unsigned short* __restrict__ wt)
{
    __shared__ unsigned short t[128][136];
    const int p = blockIdx.x;
    const float* __restrict__ W = (p == 0) ? Wq : (p == 1) ? Wk :
                                  (p == 2) ? Wv : (p == 3) ? Wg : Wo;
    const int tid = threadIdx.x;
    for (int idx = tid; idx < 16384; idx += 256) {
        int k = idx >> 7, n = idx & 127;
        t[k][n] = f2bf(W[idx]);
    }
    __syncthreads();
    unsigned short* dst = wt + (size_t)p * 16384;
    for (int idx = tid; idx < 16384; idx += 256) {
        int n = idx >> 7, k = idx & 127;
        dst[idx] = t[k][n];   // Wt[n][k] = W[k][n]
    }
}

// =====================================================================
// Kernel 0b: tri bias fp32 -> bf16 (halves the hot L2 stream in attn).
// 256 blocks x 256 thr, float4->ushort4 each.
// =====================================================================
__global__ __launch_bounds__(256, 4) void prep_tri(
    const float* __restrict__ tri, unsigned short* __restrict__ tri_bf)
{
    int idx = blockIdx.x * 256 + threadIdx.x;   // 65536 x 4 elems
    float4 v = ((const float4*)tri)[idx];
    ushort4 o;
    o.x = f2bf(v.x); o.y = f2bf(v.y); o.z = f2bf(v.z); o.w = f2bf(v.w);
    ((ushort4*)tri_bf)[idx] = o;
}

// =====================================================================
// Kernel 1: fused MFMA projections. grid (RROWS/128, 2), 256 thr.
//   pp=0: X=qx  -> q (scaled) and g (sigmoid)
//   pp=1: X=kvx -> k and v^T (vt[n][h][d][key]); vt stored as ushort4
//         packs along the row axis (C-layout rows are consecutive), so
//         no 2B scatter.
// =====================================================================
__global__ __launch_bounds__(256, 2) void proj_mfma(
    const float* __restrict__ qx, const float* __restrict__ kvx,
    const unsigned short* __restrict__ wt,
    unsigned short* __restrict__ q_ws, unsigned short* __restrict__ k_ws,
    unsigned short* __restrict__ vt_ws, unsigned short* __restrict__ g_ws)
{
    const int tid = threadIdx.x;
    const int pp = blockIdx.y;
    const float* __restrict__ X = pp ? kvx : qx;
    const unsigned short* __restrict__ WtA = wt + (size_t)(pp ? 1 : 0) * 16384;
    const unsigned short* __restrict__ WtB = wt + (size_t)(pp ? 2 : 3) * 16384;

    const int wv   = tid >> 6;
    const int lane = tid & 63;
    const int col  = lane & 15;
    const int quad = lane >> 4;
    const int r0   = blockIdx.x * 128 + wv * 32;

    f32x4v accA[2][8], accB[2][8];
#pragma unroll
    for (int mt = 0; mt < 2; ++mt)
#pragma unroll
        for (int nt = 0; nt < 8; ++nt) {
            accA[mt][nt] = (f32x4v){0.f, 0.f, 0.f, 0.f};
            accB[mt][nt] = (f32x4v){0.f, 0.f, 0.f, 0.f};
        }

#pragma unroll
    for (int kt = 0; kt < 4; ++kt) {
        frag_u a[2];
#pragma unroll
        for (int mt = 0; mt < 2; ++mt) {
            const float* src = X + (size_t)(r0 + mt * 16 + col) * 128 + kt * 32 + quad * 8;
            float4 f0 = *(const float4*)src;
            float4 f1 = *(const float4*)(src + 4);
            a[mt].v = cvt8(f0, f1);
        }
#pragma unroll
        for (int nt = 0; nt < 8; ++nt) {
            frag_u b0, b1;
            b0.u = *(const uint4*)(WtA + (size_t)(nt * 16 + col) * 128 + kt * 32 + quad * 8);
            b1.u = *(const uint4*)(WtB + (size_t)(nt * 16 + col) * 128 + kt * 32 + quad * 8);
            accA[0][nt] = __builtin_amdgcn_mfma_f32_16x16x32_bf16(a[0].v, b0.v, accA[0][nt], 0, 0, 0);
            accA[1][nt] = __builtin_amdgcn_mfma_f32_16x16x32_bf16(a[1].v, b0.v, accA[1][nt], 0, 0, 0);
            accB[0][nt] = __builtin_amdgcn_mfma_f32_16x16x32_bf16(a[0].v, b1.v, accB[0][nt], 0, 0, 0);
            accB[1][nt] = __builtin_amdgcn_mfma_f32_16x16x32_bf16(a[1].v, b1.v, accB[1][nt], 0, 0, 0);
        }
    }

    const int nn = r0 >> 8;            // n index (constant per block)
#pragma unroll
    for (int mt = 0; mt < 2; ++mt) {
        const int si0 = (r0 & 255) + mt * 16 + quad * 4;   // base row-in-n
        if (pp == 0) {
#pragma unroll
            for (int r = 0; r < 4; ++r) {
                int row = r0 + mt * 16 + quad * 4 + r;
                int si = row & 255;
#pragma unroll
                for (int nt = 0; nt < 8; ++nt) {
                    int c = nt * 16 + col;
                    int h = c >> 5, d = c & 31;
                    float qv = accA[mt][nt][r] * 0.17677669529663687f;  // 1/sqrt(32)
                    q_ws[((size_t)(nn * HH + h) * QDIM + si) * DD + d] = f2bf(qv);
                    float s = 1.0f / (1.0f + __expf(-accB[mt][nt][r]));
                    g_ws[(size_t)row * 128 + c] = f2bf(s);
                }
            }
        } else {
#pragma unroll
            for (int r = 0; r < 4; ++r) {
                int si = si0 + r;
#pragma unroll
                for (int nt = 0; nt < 8; ++nt) {
                    int c = nt * 16 + col;
                    int h = c >> 5, d = c & 31;
                    k_ws[((size_t)(nn * HH + h) * QDIM + si) * DD + d] = f2bf(accA[mt][nt][r]);
                }
            }
            // vt: pack 4 consecutive rows (keys) per ushort4 — 8B stores
#pragma unroll
            for (int nt = 0; nt < 8; ++nt) {
                int c = nt * 16 + col;
                int h = c >> 5, d = c & 31;
                ushort4 pk;
                pk.x = f2bf(accB[mt][nt][0]); pk.y = f2bf(accB[mt][nt][1]);
                pk.z = f2bf(accB[mt][nt][2]); pk.w = f2bf(accB[mt][nt][3]);
                *(ushort4*)(vt_ws + ((size_t)(nn * HH + h) * DD + d) * QDIM + si0) = pk;
            }
        }
    }
}

// =====================================================================
// Kernel 2: fused attention + gate + out-projection.
// grid 1024 (XCD-swizzled: 4 qc-blocks of each n share an XCD), 256 thr
// = 4 waves, wave = head. Per wave: 4 subtiles of 16 queries
// (QK^T MFMA with bf16-tri biases in C; in-reg softmax; chunked P->LDS;
// PV with B-frags from global vt (XCD-local L2)); gated write to shared
// Ol; one barrier; joint Ol @ Wo -> fp32 out.  LDS ~28 KB, 4 blocks/CU.
// =====================================================================
__global__ __launch_bounds__(256, 4) void attn_out(
    const unsigned short* __restrict__ q_ws, const unsigned short* __restrict__ k_ws,
    const unsigned short* __restrict__ vt_ws, const unsigned short* __restrict__ g_ws,
    const unsigned short* __restrict__ tri_bf, const float* __restrict__ mb,
    const unsigned short* __restrict__ wt, float* __restrict__ out)
{
    __shared__ unsigned short Pl[4][16 * 80];   // per-wave P chunk, 10.2 KB
    __shared__ unsigned short Ol[64 * 136];     // gated O [q][c], 17.4 KB

    const int tid = threadIdx.x;
    const int b   = blockIdx.x;
    const int xcd = b & 7;
    const int t   = b >> 3;          // 0..127
    const int qc  = t & 3;
    const int n   = (t >> 2) * 8 + xcd;

    const int wv   = tid >> 6;   // wave = head
    const int h    = wv;
    const int lane = tid & 63;
    const int col  = lane & 15;
    const int quad = lane >> 4;
    const size_t base  = (size_t)(n * HH + h) * QDIM * DD;   // q,k [seq][d]
    const size_t vbase = (size_t)(n * HH + h) * DD * QDIM;   // vt [d][seq]
    unsigned short* Pw = &Pl[wv][0];

    for (int st = 0; st < 4; ++st) {
        const int qg = qc * 64 + st * 16 + col;   // this lane's query (B col)

        frag_u bq;
        bq.u = *(const uint4*)(q_ws + base + (size_t)qg * DD + quad * 8);

        // S^T tiles: 16 m-tiles of keys; C init = tri(bf16) + mb
        f32x4v acc[16];
#pragma unroll
        for (int mt = 0; mt < 16; ++mt) {
            int k0 = mt * 16 + quad * 4;
            ushort4 tb = *(const ushort4*)&tri_bf[((size_t)(h * 256 + qg)) * 256 + k0];
            float4 m4 = *(const float4*)&mb[n * 256 + k0];
            f32x4v c;
            c[0] = bf2f(tb.x) + m4.x; c[1] = bf2f(tb.y) + m4.y;
            c[2] = bf2f(tb.z) + m4.z; c[3] = bf2f(tb.w) + m4.w;
            frag_u ak;
            ak.u = *(const uint4*)(k_ws + base + (size_t)(mt * 16 + col) * DD + quad * 8);
            acc[mt] = __builtin_amdgcn_mfma_f32_16x16x32_bf16(ak.v, bq.v, c, 0, 0, 0);
        }

        // softmax over keys: per-lane 64 vals + cross-quad shfl
        float mx = -1e30f;
#pragma unroll
        for (int mt = 0; mt < 16; ++mt)
#pragma unroll
            for (int r = 0; r < 4; ++r) mx = fmaxf(mx, acc[mt][r]);
        mx = fmaxf(mx, __shfl_xor(mx, 16));
        mx = fmaxf(mx, __shfl_xor(mx, 32));

        float sum = 0.f;
#pragma unroll
        for (int mt = 0; mt < 16; ++mt)
#pragma unroll
            for (int r = 0; r < 4; ++r) {
                float e = __expf(acc[mt][r] - mx);
                acc[mt][r] = e;
                sum += e;
            }
        sum += __shfl_xor(sum, 16);
        sum += __shfl_xor(sum, 32);
        float inv = 1.0f / sum;   // for query `col` of this subtile

        // chunked P pack + PV (vt B-frags from global / XCD-local L2)
        f32x4v o0 = {0.f, 0.f, 0.f, 0.f};
        f32x4v o1 = {0.f, 0.f, 0.f, 0.f};
#pragma unroll
        for (int cc = 0; cc < 4; ++cc) {
#pragma unroll
            for (int j = 0; j < 4; ++j) {
                int mt = cc * 4 + j;
                ushort4 pk;
                pk.x = f2bf(acc[mt][0]); pk.y = f2bf(acc[mt][1]);
                pk.z = f2bf(acc[mt][2]); pk.w = f2bf(acc[mt][3]);
                *(ushort4*)&Pw[col * 80 + j * 16 + quad * 4] = pk;
            }
#pragma unroll
            for (int j2 = 0; j2 < 2; ++j2) {
                int kc = cc * 2 + j2;
                frag_u ap, b0, b1;
                ap.u = *(const uint4*)&Pw[col * 80 + j2 * 32 + quad * 8];
                b0.u = *(const uint4*)(vt_ws + vbase + (size_t)col * QDIM + kc * 32 + quad * 8);
                b1.u = *(const uint4*)(vt_ws + vbase + (size_t)(16 + col) * QDIM + kc * 32 + quad * 8);
                o0 = __builtin_amdgcn_mfma_f32_16x16x32_bf16(ap.v, b0.v, o0, 0, 0, 0);
                o1 = __builtin_amdgcn_mfma_f32_16x16x32_bf16(ap.v, b1.v, o1, 0, 0, 0);
            }
        }

        // normalize, gate, write to shared Ol (wave owns cols h*32..+31)
#pragma unroll
        for (int r = 0; r < 4; ++r) {
            int qi = st * 16 + quad * 4 + r;          // row within 64-block
            float iv = __shfl(inv, quad * 4 + r);     // inv of that query
            size_t grow = ((size_t)(n * 256 + qc * 64 + qi)) * 128 + h * 32;
            float g0 = bf2f(g_ws[grow + col]);
            Ol[qi * 136 + h * 32 + col] = f2bf(o0[r] * iv * g0);
            float g1 = bf2f(g_ws[grow + 16 + col]);
            Ol[qi * 136 + h * 32 + 16 + col] = f2bf(o1[r] * iv * g1);
        }
    }

    __syncthreads();

    // ---- joint out-projection: out[64x128] = Ol(bf16) @ Wo ----
    const unsigned short* __restrict__ Wt = wt + 4 * 16384;
    f32x4v acc2[8];
#pragma unroll
    for (int nt = 0; nt < 8; ++nt) acc2[nt] = (f32x4v){0.f, 0.f, 0.f, 0.f};

#pragma unroll
    for (int kt = 0; kt < 4; ++kt) {
        frag_u a;
        a.u = *(const uint4*)&Ol[(wv * 16 + col) * 136 + kt * 32 + quad * 8];
#pragma unroll
        for (int nt = 0; nt < 8; ++nt) {
            frag_u bb;
            bb.u = *(const uint4*)(Wt + (size_t)(nt * 16 + col) * 128 + kt * 32 + quad * 8);
            acc2[nt] = __builtin_amdgcn_mfma_f32_16x16x32_bf16(a.v, bb.v, acc2[nt], 0, 0, 0);
        }
    }

#pragma unroll
    for (int r = 0; r < 4; ++r) {
        size_t row = (size_t)(n * 256 + qc * 64 + wv * 16 + quad * 4 + r);
#pragma unroll
        for (int nt = 0; nt < 8; ++nt)
            out[row * 128 + nt * 16 + col] = acc2[nt][r];
    }
}

// =====================================================================
extern "C" void kernel_launch(void* const* d_in, const int* in_sizes, int n_in,
                              void* d_out, int out_size, void* d_ws, size_t ws_size,
                              hipStream_t stream) {
    const float* qx  = (const float*)d_in[0];
    const float* kvx = (const float*)d_in[1];
    const float* tri = (const float*)d_in[2];
    const float* mb  = (const float*)d_in[3];
    // d_in[4] = mask (unused: mask_bias carries it in the reference path)
    const float* Wq  = (const float*)d_in[5];
    const float* Wk  = (const float*)d_in[6];
    const float* Wv  = (const float*)d_in[7];
    const float* Wg  = (const float*)d_in[8];
    const float* Wo  = (const float*)d_in[9];
    float* out = (float*)d_out;

    unsigned short* ws = (unsigned short*)d_ws;
    const size_t RC = (size_t)RROWS * 128;
    unsigned short* q_ws   = ws;            // [n][h][q][32]
    unsigned short* k_ws   = ws + RC;       // [n][h][k][32]
    unsigned short* vt_ws  = ws + 2 * RC;   // [n][h][32][key]  (transposed V)
    unsigned short* g_ws   = ws + 3 * RC;   // [n][q][128]
    unsigned short* wt     = ws + 4 * RC;   // 5 x [128][128] bf16 transposed weights
    unsigned short* tri_bf = wt + 5 * 16384;  // [H][256][256] bf16 tri bias

    prep_weights<<<dim3(5), 256, 0, stream>>>(Wq, Wk, Wv, Wg, Wo, wt);
    prep_tri<<<dim3(256), 256, 0, stream>>>(tri, tri_bf);
    proj_mfma<<<dim3(RROWS / 128, 2), 256, 0, stream>>>(
        qx, kvx, wt, q_ws, k_ws, vt_ws, g_ws);
    attn_out<<<dim3(1024), 256, 0, stream>>>(
        q_ws, k_ws, vt_ws, g_ws, tri_bf, mb, wt, out);
}

// Round 7
// 282.527 us; speedup vs baseline: 1.4756x; 1.4756x over previous
//
#include <hip/hip_runtime.h>
#include <hip/hip_bf16.h>

// Problem constants
#define NDIM 256   // outer n
#define QDIM 256   // q/k sequence
#define CDIM 128   // channels
#define HH 4       // heads
#define DD 32      // head dim
#define RROWS (NDIM * QDIM)  // 65536 flattened rows

// ---------- bf16 helpers ----------
__device__ __forceinline__ float bf2f(unsigned short u) {
    unsigned int x = ((unsigned int)u) << 16;
    return __uint_as_float(x);
}
__device__ __forceinline__ unsigned short f2bf(float f) {
    union { __bf16 b; unsigned short u; } cv;
    cv.b = (__bf16)f;   // HW RNE convert
    return cv.u;
}

// MFMA fragment types (gfx950: mfma_f32_16x16x32_bf16)
typedef __bf16 bf16x8v __attribute__((ext_vector_type(8)));
typedef float  f32x4v  __attribute__((ext_vector_type(4)));
union frag_u { uint4 u; bf16x8v v; };

__device__ __forceinline__ bf16x8v cvt8(float4 f0, float4 f1) {
    bf16x8v r;
    r[0] = (__bf16)f0.x; r[1] = (__bf16)f0.y; r[2] = (__bf16)f0.z; r[3] = (__bf16)f0.w;
    r[4] = (__bf16)f1.x; r[5] = (__bf16)f1.y; r[6] = (__bf16)f1.z; r[7] = (__bf16)f1.w;
    return r;
}

// =====================================================================
// Kernel 0a: weight prep. One block per matrix (5 blocks).
// wt[p][n][k] = bf16(W_p[k][n])   (transposed so B-frags are contiguous)
// =====================================================================
__global__ __launch_bounds__(256, 1) void prep_weights(
    const float* __restrict__ Wq, const float* __restrict__ Wk,
    const float* __restrict__ Wv, const float* __restrict__ Wg,
    const float* __restrict__ Wo, unsigned short* __restrict__ wt)
{
    __shared__ unsigned short t[128][136];
    const int p = blockIdx.x;
    const float* __restrict__ W = (p == 0) ? Wq : (p == 1) ? Wk :
                                  (p == 2) ? Wv : (p == 3) ? Wg : Wo;
    const int tid = threadIdx.x;
    for (int idx = tid; idx < 16384; idx += 256) {
        int k = idx >> 7, n = idx & 127;
        t[k][n] = f2bf(W[idx]);
    }
    __syncthreads();
    unsigned short* dst = wt + (size_t)p * 16384;
    for (int idx = tid; idx < 16384; idx += 256) {
        int n = idx >> 7, k = idx & 127;
        dst[idx] = t[k][n];   // Wt[n][k] = W[k][n]
    }
}

// =====================================================================
// Kernel 0b: tri bias fp32 -> bf16 (halves the hot L2 stream in attn).
// =====================================================================
__global__ __launch_bounds__(256, 4) void prep_tri(
    const float* __restrict__ tri, unsigned short* __restrict__ tri_bf)
{
    int idx = blockIdx.x * 256 + threadIdx.x;   // 65536 float4 total
    float4 v = ((const float4*)tri)[idx];
    ushort4 o;
    o.x = f2bf(v.x); o.y = f2bf(v.y); o.z = f2bf(v.z); o.w = f2bf(v.w);
    ((ushort4*)tri_bf)[idx] = o;
}

// =====================================================================
// Kernel 1: fused MFMA projections. grid (RROWS/128, 2), 256 thr.
//   pp=0: X=qx  -> q (scaled) and g (sigmoid)
//   pp=1: X=kvx -> k and v^T (vt[n][h][d][key]); vt stored as ushort4
//         packed along keys (C-layout rows are consecutive) — 8B stores.
// =====================================================================
__global__ __launch_bounds__(256, 2) void proj_mfma(
    const float* __restrict__ qx, const float* __restrict__ kvx,
    const unsigned short* __restrict__ wt,
    unsigned short* __restrict__ q_ws, unsigned short* __restrict__ k_ws,
    unsigned short* __restrict__ vt_ws, unsigned short* __restrict__ g_ws)
{
    const int tid = threadIdx.x;
    const int pp = blockIdx.y;
    const float* __restrict__ X = pp ? kvx : qx;
    const unsigned short* __restrict__ WtA = wt + (size_t)(pp ? 1 : 0) * 16384;
    const unsigned short* __restrict__ WtB = wt + (size_t)(pp ? 2 : 3) * 16384;

    const int wv   = tid >> 6;
    const int lane = tid & 63;
    const int col  = lane & 15;
    const int quad = lane >> 4;
    const int r0   = blockIdx.x * 128 + wv * 32;

    f32x4v accA[2][8], accB[2][8];
#pragma unroll
    for (int mt = 0; mt < 2; ++mt)
#pragma unroll
        for (int nt = 0; nt < 8; ++nt) {
            accA[mt][nt] = (f32x4v){0.f, 0.f, 0.f, 0.f};
            accB[mt][nt] = (f32x4v){0.f, 0.f, 0.f, 0.f};
        }

#pragma unroll
    for (int kt = 0; kt < 4; ++kt) {
        frag_u a[2];
#pragma unroll
        for (int mt = 0; mt < 2; ++mt) {
            const float* src = X + (size_t)(r0 + mt * 16 + col) * 128 + kt * 32 + quad * 8;
            float4 f0 = *(const float4*)src;
            float4 f1 = *(const float4*)(src + 4);
            a[mt].v = cvt8(f0, f1);
        }
#pragma unroll
        for (int nt = 0; nt < 8; ++nt) {
            frag_u b0, b1;
            b0.u = *(const uint4*)(WtA + (size_t)(nt * 16 + col) * 128 + kt * 32 + quad * 8);
            b1.u = *(const uint4*)(WtB + (size_t)(nt * 16 + col) * 128 + kt * 32 + quad * 8);
            accA[0][nt] = __builtin_amdgcn_mfma_f32_16x16x32_bf16(a[0].v, b0.v, accA[0][nt], 0, 0, 0);
            accA[1][nt] = __builtin_amdgcn_mfma_f32_16x16x32_bf16(a[1].v, b0.v, accA[1][nt], 0, 0, 0);
            accB[0][nt] = __builtin_amdgcn_mfma_f32_16x16x32_bf16(a[0].v, b1.v, accB[0][nt], 0, 0, 0);
            accB[1][nt] = __builtin_amdgcn_mfma_f32_16x16x32_bf16(a[1].v, b1.v, accB[1][nt], 0, 0, 0);
        }
    }

    const int nn = r0 >> 8;            // n index (constant per block)
#pragma unroll
    for (int mt = 0; mt < 2; ++mt) {
        const int si0 = (r0 & 255) + mt * 16 + quad * 4;   // base row-in-n
        if (pp == 0) {
#pragma unroll
            for (int r = 0; r < 4; ++r) {
                int row = r0 + mt * 16 + quad * 4 + r;
                int si = row & 255;
#pragma unroll
                for (int nt = 0; nt < 8; ++nt) {
                    int c = nt * 16 + col;
                    int h = c >> 5, d = c & 31;
                    float qv = accA[mt][nt][r] * 0.17677669529663687f;  // 1/sqrt(32)
                    q_ws[((size_t)(nn * HH + h) * QDIM + si) * DD + d] = f2bf(qv);
                    float s = 1.0f / (1.0f + __expf(-accB[mt][nt][r]));
                    g_ws[(size_t)row * 128 + c] = f2bf(s);
                }
            }
        } else {
#pragma unroll
            for (int r = 0; r < 4; ++r) {
                int si = si0 + r;
#pragma unroll
                for (int nt = 0; nt < 8; ++nt) {
                    int c = nt * 16 + col;
                    int h = c >> 5, d = c & 31;
                    k_ws[((size_t)(nn * HH + h) * QDIM + si) * DD + d] = f2bf(accA[mt][nt][r]);
                }
            }
            // vt: pack 4 consecutive keys per ushort4 — 8B stores
#pragma unroll
            for (int nt = 0; nt < 8; ++nt) {
                int c = nt * 16 + col;
                int h = c >> 5, d = c & 31;
                ushort4 pk;
                pk.x = f2bf(accB[mt][nt][0]); pk.y = f2bf(accB[mt][nt][1]);
                pk.z = f2bf(accB[mt][nt][2]); pk.w = f2bf(accB[mt][nt][3]);
                *(ushort4*)(vt_ws + ((size_t)(nn * HH + h) * DD + d) * QDIM + si0) = pk;
            }
        }
    }
}

// =====================================================================
// Kernel 2: MFMA attention. 4096 blocks (XCD-swizzled: all 16 tiles of
// an n on one XCD), 256 thr = 4 waves; block = (qc, n, h), wave = 16 q.
//  - V^T staged from vt_ws via contiguous uint4 copy (conflict-free).
//  - S^T = K q^T; C init = bf16 tri + fp32 mb; in-reg shfl softmax.
//  - Full P pack to wave-private LDS (16 stores), then 8 PV MFMA iters
//    (R3's better-pipelined shape; no chunk serialization).
// =====================================================================
__global__ __launch_bounds__(256, 3) void attn_kernel(
    const unsigned short* __restrict__ q_ws, const unsigned short* __restrict__ k_ws,
    const unsigned short* __restrict__ vt_ws, const unsigned short* __restrict__ g_ws,
    const unsigned short* __restrict__ tri_bf, const float* __restrict__ mb,
    unsigned short* __restrict__ o_ws)
{
    __shared__ unsigned short vl[32 * 264];     // V^T [d][key], 16.9 KB
    __shared__ unsigned short Pl[4][16 * 264];  // per-wave P [q][key], 33.8 KB

    const int tid = threadIdx.x;
    const int b   = blockIdx.x;
    const int xcd = b & 7;
    const int t   = b >> 3;          // 0..511
    const int u   = t & 15;
    const int n   = (t >> 4) * 8 + xcd;
    const int qc  = u >> 2;
    const int h   = u & 3;

    const size_t base  = (size_t)(n * HH + h) * QDIM * DD;   // q,k [seq][d]
    const size_t vbase = (size_t)(n * HH + h) * DD * QDIM;   // vt [d][seq]

    // ---- stage V^T: contiguous copy, 1024 uint4 total ----
#pragma unroll
    for (int i = 0; i < 4; ++i) {
        int idx = tid + i * 256;      // [0,1024)
        int d = idx >> 5;             // 32 uint4 per d-row
        int g = idx & 31;
        uint4 raw = *(const uint4*)(vt_ws + vbase + (size_t)d * QDIM + g * 8);
        *(uint4*)&vl[d * 264 + g * 8] = raw;
    }
    __syncthreads();

    const int wv   = tid >> 6;
    const int lane = tid & 63;
    const int col  = lane & 15;
    const int quad = lane >> 4;
    const int qg   = qc * 64 + wv * 16 + col;   // this lane's query (B col)

    // ---- B frag: q[query=col][d = quad*8 + 0..7]
    frag_u bq;
    bq.u = *(const uint4*)(q_ws + base + (size_t)qg * DD + quad * 8);

    // ---- S^T tiles: 16 m-tiles of keys; C init = tri(bf16) + mb
    f32x4v acc[16];
#pragma unroll
    for (int mt = 0; mt < 16; ++mt) {
        int k0 = mt * 16 + quad * 4;
        ushort4 tb = *(const ushort4*)&tri_bf[((size_t)(h * 256 + qg)) * 256 + k0];
        float4 m4 = *(const float4*)&mb[n * 256 + k0];
        f32x4v c;
        c[0] = bf2f(tb.x) + m4.x; c[1] = bf2f(tb.y) + m4.y;
        c[2] = bf2f(tb.z) + m4.z; c[3] = bf2f(tb.w) + m4.w;
        frag_u ak;
        ak.u = *(const uint4*)(k_ws + base + (size_t)(mt * 16 + col) * DD + quad * 8);
        acc[mt] = __builtin_amdgcn_mfma_f32_16x16x32_bf16(ak.v, bq.v, c, 0, 0, 0);
    }

    // ---- softmax over keys (rows of S^T): per-lane + cross-quad shfl
    float mx = -1e30f;
#pragma unroll
    for (int mt = 0; mt < 16; ++mt)
#pragma unroll
        for (int r = 0; r < 4; ++r) mx = fmaxf(mx, acc[mt][r]);
    mx = fmaxf(mx, __shfl_xor(mx, 16));
    mx = fmaxf(mx, __shfl_xor(mx, 32));

    float sum = 0.f;
#pragma unroll
    for (int mt = 0; mt < 16; ++mt)
#pragma unroll
        for (int r = 0; r < 4; ++r) {
            float e = __expf(acc[mt][r] - mx);
            acc[mt][r] = e;
            sum += e;
        }
    sum += __shfl_xor(sum, 16);
    sum += __shfl_xor(sum, 32);
    float inv = 1.0f / sum;   // inv for query `col` (lane-indexed)

    // ---- full P pack to wave-private LDS (16 b64 stores) ----
    unsigned short* Pw = &Pl[wv][0];
#pragma unroll
    for (int mt = 0; mt < 16; ++mt) {
        ushort4 pk;
        pk.x = f2bf(acc[mt][0]); pk.y = f2bf(acc[mt][1]);
        pk.z = f2bf(acc[mt][2]); pk.w = f2bf(acc[mt][3]);
        *(ushort4*)&Pw[col * 264 + mt * 16 + quad * 4] = pk;
    }

    // ---- O = P V : M=16 queries, N=32 d (2 tiles), K=256 (8 steps) ----
    f32x4v o0 = {0.f, 0.f, 0.f, 0.f};
    f32x4v o1 = {0.f, 0.f, 0.f, 0.f};
#pragma unroll
    for (int kc = 0; kc < 8; ++kc) {
        frag_u ap, b0, b1;
        ap.u = *(const uint4*)&Pw[col * 264 + kc * 32 + quad * 8];
        b0.u = *(const uint4*)&vl[col * 264 + kc * 32 + quad * 8];
        b1.u = *(const uint4*)&vl[(16 + col) * 264 + kc * 32 + quad * 8];
        o0 = __builtin_amdgcn_mfma_f32_16x16x32_bf16(ap.v, b0.v, o0, 0, 0, 0);
        o1 = __builtin_amdgcn_mfma_f32_16x16x32_bf16(ap.v, b1.v, o1, 0, 0, 0);
    }

    // ---- epilogue: normalize, gate, store bf16 ----
#pragma unroll
    for (int r = 0; r < 4; ++r) {
        int qi = quad * 4 + r;                       // query within wave tile
        int qglob = qc * 64 + wv * 16 + qi;
        float iv = __shfl(inv, qi);                  // inv of that query
        size_t ob = ((size_t)(n * 256 + qglob)) * 128 + h * 32;
        float g0 = bf2f(g_ws[ob + col]);
        o_ws[ob + col] = f2bf(o0[r] * iv * g0);
        float g1 = bf2f(g_ws[ob + 16 + col]);
        o_ws[ob + 16 + col] = f2bf(o1[r] * iv * g1);
    }
}

// =====================================================================
// Kernel 3: MFMA out-projection. grid RROWS/128, 256 thr, no LDS.
// out[65536x128] fp32 = o_ws(bf16) @ Wo  (B-frags from wt[4])
// =====================================================================
__global__ __launch_bounds__(256, 4) void outproj_mfma(
    const unsigned short* __restrict__ o_ws, const unsigned short* __restrict__ wt,
    float* __restrict__ out)
{
    const int tid = threadIdx.x;
    const unsigned short* __restrict__ Wt = wt + 4 * 16384;

    const int wv   = tid >> 6;
    const int lane = tid & 63;
    const int col  = lane & 15;
    const int quad = lane >> 4;
    const int r0   = blockIdx.x * 128 + wv * 32;

    f32x4v acc[2][8];
#pragma unroll
    for (int mt = 0; mt < 2; ++mt)
#pragma unroll
        for (int nt = 0; nt < 8; ++nt)
            acc[mt][nt] = (f32x4v){0.f, 0.f, 0.f, 0.f};

#pragma unroll
    for (int kt = 0; kt < 4; ++kt) {
        frag_u a[2];
#pragma unroll
        for (int mt = 0; mt < 2; ++mt)
            a[mt].u = *(const uint4*)(o_ws + (size_t)(r0 + mt * 16 + col) * 128 + kt * 32 + quad * 8);
#pragma unroll
        for (int nt = 0; nt < 8; ++nt) {
            frag_u b;
            b.u = *(const uint4*)(Wt + (size_t)(nt * 16 + col) * 128 + kt * 32 + quad * 8);
            acc[0][nt] = __builtin_amdgcn_mfma_f32_16x16x32_bf16(a[0].v, b.v, acc[0][nt], 0, 0, 0);
            acc[1][nt] = __builtin_amdgcn_mfma_f32_16x16x32_bf16(a[1].v, b.v, acc[1][nt], 0, 0, 0);
        }
    }

#pragma unroll
    for (int mt = 0; mt < 2; ++mt)
#pragma unroll
        for (int r = 0; r < 4; ++r) {
            size_t row = r0 + mt * 16 + quad * 4 + r;
#pragma unroll
            for (int nt = 0; nt < 8; ++nt)
                out[row * 128 + nt * 16 + col] = acc[mt][nt][r];
        }
}

// =====================================================================
extern "C" void kernel_launch(void* const* d_in, const int* in_sizes, int n_in,
                              void* d_out, int out_size, void* d_ws, size_t ws_size,
                              hipStream_t stream) {
    const float* qx  = (const float*)d_in[0];
    const float* kvx = (const float*)d_in[1];
    const float* tri = (const float*)d_in[2];
    const float* mb  = (const float*)d_in[3];
    // d_in[4] = mask (unused: mask_bias carries it in the reference path)
    const float* Wq  = (const float*)d_in[5];
    const float* Wk  = (const float*)d_in[6];
    const float* Wv  = (const float*)d_in[7];
    const float* Wg  = (const float*)d_in[8];
    const float* Wo  = (const float*)d_in[9];
    float* out = (float*)d_out;

    unsigned short* ws = (unsigned short*)d_ws;
    const size_t RC = (size_t)RROWS * 128;
    unsigned short* q_ws   = ws;            // [n][h][q][32]
    unsigned short* k_ws   = ws + RC;       // [n][h][k][32]
    unsigned short* vt_ws  = ws + 2 * RC;   // [n][h][32][key]  (transposed V)
    unsigned short* g_ws   = ws + 3 * RC;   // [n][q][128]
    unsigned short* o_ws   = ws + 4 * RC;   // [n][q][128]
    unsigned short* wt     = ws + 5 * RC;   // 5 x [128][128] bf16 weights^T
    unsigned short* tri_bf = wt + 5 * 16384;  // [H][256][256] bf16 tri bias

    prep_weights<<<dim3(5), 256, 0, stream>>>(Wq, Wk, Wv, Wg, Wo, wt);
    prep_tri<<<dim3(256), 256, 0, stream>>>(tri, tri_bf);
    proj_mfma<<<dim3(RROWS / 128, 2), 256, 0, stream>>>(
        qx, kvx, wt, q_ws, k_ws, vt_ws, g_ws);
    attn_kernel<<<dim3(4 * NDIM * HH), 256, 0, stream>>>(
        q_ws, k_ws, vt_ws, g_ws, tri_bf, mb, o_ws);
    outproj_mfma<<<dim3(RROWS / 128), 256, 0, stream>>>(o_ws, wt, out);
}